// Round 6
// baseline (756.421 us; speedup 1.0000x reference)
//
#include <hip/hip_runtime.h>
#include <cstdint>
#include <cstddef>

// ---------------- types / helpers ----------------
typedef __bf16 bf16x8 __attribute__((ext_vector_type(8)));
typedef float f32x4 __attribute__((ext_vector_type(4)));

__device__ __forceinline__ unsigned short f2bf(float f) {
  unsigned u = __float_as_uint(f);
  u += 0x7fffu + ((u >> 16) & 1u);   // RNE
  return (unsigned short)(u >> 16);
}
__device__ __forceinline__ float bf2f(unsigned short s) {
  return __uint_as_float(((unsigned)s) << 16);
}

// async global->LDS, 16B per lane, linear dest (wave-uniform base + lane*16)
__device__ __forceinline__ void gld_lds16(const void* g, void* l) {
  __builtin_amdgcn_global_load_lds(
      (const __attribute__((address_space(1))) void*)g,
      (__attribute__((address_space(3))) void*)l, 16, 0, 0);
}

#define BARM() do { __builtin_amdgcn_s_barrier(); asm volatile("" ::: "memory"); } while (0)
#define VMCNT(n) asm volatile("s_waitcnt vmcnt(" #n ")" ::: "memory")
#define LGKM0()  do { asm volatile("s_waitcnt lgkmcnt(0)" ::: "memory"); \
                      __builtin_amdgcn_sched_barrier(0); } while (0)

// ---------------- pack W [K][N] f32 -> Wp fragment-linear bf16 ----------------
// Wp element for (n,k): nt=n/16, kq=k/32, lane=(n%16)+((k%32)/8)*16, e=k%8
// -> Wp[((nt*KQ + kq)*64 + lane)*8 + e]. A wave's B-frag (16 rows x k32-slice)
// is then ONE coalesced 1KB chunk: base + lane*16B.
__global__ void pack_w(const float* __restrict__ w, unsigned short* __restrict__ wp,
                       int K, int N) {
  __shared__ float tile[32][33];
  int nt32 = N >> 5;
  int bx = blockIdx.x % nt32;   // n 32-tile
  int by = blockIdx.x / nt32;   // k 32-tile == kq
  int tx = threadIdx.x & 31, ty = threadIdx.x >> 5;  // 32x8
#pragma unroll
  for (int r = 0; r < 32; r += 8)
    tile[ty + r][tx] = w[(size_t)(by * 32 + ty + r) * N + bx * 32 + tx];  // [k-loc][n-loc]
  __syncthreads();
  int KQ = K >> 5;
  int flat = threadIdx.x * 4;          // 1024 bf16 out per 32x32 tile
  int c = flat >> 9;                   // n-half -> nt = bx*2 + c
  int l = (flat >> 3) & 63;
  int e0 = flat & 7;                   // 0 or 4
  int nl = c * 16 + (l & 15);
  int kl = (l >> 4) * 8 + e0;
  unsigned short* o = wp + ((size_t)((bx * 2 + c) * KQ + by) * 64 + l) * 8 + e0;
#pragma unroll
  for (int e = 0; e < 4; ++e) o[e] = f2bf(tile[kl + e][nl]);
}

// ---------------- x f32 -> bf16 (chunk, zero-pad rows >= nvalid) ----------------
__global__ void cvt_x(const float* __restrict__ x, unsigned short* __restrict__ xb,
                      int rows, int nvalid, int D) {
  size_t total = (size_t)rows * D / 8;
  for (size_t i = (size_t)blockIdx.x * blockDim.x + threadIdx.x; i < total;
       i += (size_t)gridDim.x * blockDim.x) {
    size_t e = i * 8;
    int row = (int)(e / (size_t)D);
    uint4 ov;
    if (row < nvalid) {
      const float4* s = (const float4*)(x + e);
      float4 v0 = s[0], v1 = s[1];
      ov.x = (unsigned)f2bf(v0.x) | ((unsigned)f2bf(v0.y) << 16);
      ov.y = (unsigned)f2bf(v0.z) | ((unsigned)f2bf(v0.w) << 16);
      ov.z = (unsigned)f2bf(v1.x) | ((unsigned)f2bf(v1.y) << 16);
      ov.w = (unsigned)f2bf(v1.z) | ((unsigned)f2bf(v1.w) << 16);
    } else {
      ov.x = ov.y = ov.z = ov.w = 0u;
    }
    *(uint4*)(xb + e) = ov;
  }
}

// ---------------- 256x128 GEMM, A-only LDS, B from packed global ----------------
// 256 threads = 4 waves (2M x 2N); per-wave output 128x64; BK=32.
// Round-5 lesson: LDS is the per-CU shared pipe and was over-subscribed
// (770 cyc LDS vs 620 cyc MFMA per block-tile). B now streams from the
// L2-resident packed Wp straight to VGPRs (1 coalesced dwordx4 per frag,
// prefetched one K-tile ahead into named regs), so per-tile LDS drops to
// ~515 cyc < MFMA -> with 2 blocks/CU the CU is MFMA-bound.
// LDS: 2 slots x A[256][32] bf16 = 32 KiB -> 2 blocks/CU at (256,2).
__device__ __forceinline__ bf16x8 read_frag(const unsigned short* region, int row, int kel) {
  int ke = kel ^ (((row >> 1) & 3) << 3);
  return *(const bf16x8*)(region + row * 32 + ke);
}

__device__ __forceinline__ void stage_a(const unsigned short* gpanel, int K, int kofs,
                                        unsigned short* region, int tid) {
#pragma unroll
  for (int r = 0; r < 4; ++r) {
    int row = r * 64 + (tid >> 2);
    int ke = ((tid & 3) * 8) ^ (((row >> 1) & 3) << 3);  // inverse-swizzled source
    gld_lds16(gpanel + (size_t)row * K + kofs + ke, region + r * 2048 + tid * 8);
  }
}

__device__ __forceinline__ void load_b4(const unsigned short* wpb, int KQ, int kq, int l,
                                        bf16x8* b) {
#pragma unroll
  for (int nn = 0; nn < 4; ++nn)
    b[nn] = *(const bf16x8*)(wpb + ((size_t)(nn * KQ + kq) * 64 + l) * 8);
}

__global__ __launch_bounds__(256, 2) void gemm_blds(
    const unsigned short* __restrict__ A,   // [M][K] bf16
    const unsigned short* __restrict__ Wp,  // packed [N/16][K/32][64][8] bf16
    const float* __restrict__ bias,         // [N] f32
    unsigned short* __restrict__ C,         // [M][N] bf16
    int N, int K) {
  __shared__ alignas(16) unsigned short lds[2][8192];   // 32 KiB (A only)
  const int tid = threadIdx.x;
  const int w = tid >> 6, l = tid & 63;
  const int wm = w >> 1, wn = w & 1;
  const int lc = l & 15, lk8 = (l >> 4) * 8;

  // T1: bijective XCD swizzle (m204); bn-fast so an XCD chunk reuses A panels.
  const int nbn = N >> 7;
  const int nwg = gridDim.x;
  const int q = nwg >> 3, rr = nwg & 7;
  const int xcd = blockIdx.x & 7, ib = blockIdx.x >> 3;
  const int bswz = (xcd < rr ? xcd * (q + 1) : rr * (q + 1) + (xcd - rr) * q) + ib;
  const int bm = bswz / nbn, bn = bswz - bm * nbn;

  const unsigned short* Ap = A + (size_t)bm * 256 * K;
  const int KQ = K >> 5;
  const unsigned short* wpb = Wp + ((size_t)(bn * 8 + wn * 4) * KQ * 64) * 8;
  const int T = KQ;

  f32x4 acc[8][4] = {};
  bf16x8 a[8], bc[4], bn_[4];

  // prologue: A tile0 -> slot0; B frags for kq=0 -> bc
  stage_a(Ap, K, 0, &lds[0][0], tid);
  load_b4(wpb, KQ, 0, l, bc);
  VMCNT(0);
  BARM();

#define TILE_BODY(TT, SRD, SWR, BCUR, BNXT)                                      \
  do {                                                                           \
    _Pragma("unroll") for (int mm = 0; mm < 8; ++mm)                             \
        a[mm] = read_frag(SRD, wm * 128 + mm * 16 + lc, lk8);                    \
    if ((TT) + 1 < T) {                                                          \
      stage_a(Ap, K, ((TT) + 1) * 32, SWR, tid);                                 \
      load_b4(wpb, KQ, (TT) + 1, l, BNXT);                                       \
    }                                                                            \
    BARM();                                                                      \
    LGKM0();                                                                     \
    __builtin_amdgcn_s_setprio(1);                                               \
    _Pragma("unroll") for (int mm = 0; mm < 8; ++mm)                             \
        _Pragma("unroll") for (int nn = 0; nn < 4; ++nn)                         \
            acc[mm][nn] = __builtin_amdgcn_mfma_f32_16x16x32_bf16(               \
                a[mm], BCUR[nn], acc[mm][nn], 0, 0, 0);                          \
    __builtin_amdgcn_s_setprio(0);                                               \
    VMCNT(0);                                                                    \
    BARM();                                                                      \
  } while (0)

  for (int t = 0; t < T; t += 2) {
    TILE_BODY(t, &lds[0][0], &lds[1][0], bc, bn_);        // even tile: read slot0
    if (t + 1 < T)
      TILE_BODY(t + 1, &lds[1][0], &lds[0][0], bn_, bc);  // odd tile: read slot1
  }
#undef TILE_BODY

  // ---- epilogue: acc -> LDS (granule-XOR) -> coalesced dwordx4 stores ----
  // eps = [128][128] bf16 = 32 KiB (the whole LDS, both slots).
  unsigned short* eps = &lds[0][0];
  float bv[4];
#pragma unroll
  for (int nn = 0; nn < 4; ++nn) bv[nn] = bias[bn * 128 + wn * 64 + nn * 16 + lc];

#pragma unroll
  for (int r = 0; r < 2; ++r) {
    if (wm == r) {
#pragma unroll
      for (int mm = 0; mm < 8; ++mm) {
#pragma unroll
        for (int nn = 0; nn < 4; ++nn) {
          int lcol = wn * 64 + nn * 16 + lc;
#pragma unroll
          for (int j = 0; j < 4; ++j) {
            int lrow = mm * 16 + (l >> 4) * 4 + j;
            int g = lcol >> 3, e = lcol & 7;
            float v = fmaxf(acc[mm][nn][j] + bv[nn], 0.0f);
            eps[lrow * 128 + ((g ^ (lrow & 15)) << 3) + e] = f2bf(v);
          }
        }
      }
    }
    BARM();
#pragma unroll
    for (int it = 0; it < 8; ++it) {
      int flat = it * 256 + tid;          // 2048 = 128 rows x 16 col-granules
      int lrow = flat >> 4, cb = flat & 15;
      uint4 v = *(const uint4*)&eps[lrow * 128 + (((cb ^ (lrow & 15))) << 3)];
      *(uint4*)&C[(size_t)(bm * 256 + r * 128 + lrow) * N + bn * 128 + cb * 8] = v;
    }
    BARM();
  }
}

// ---------------- segment mean pool (split: S sub-blocks per graph + reduce) ----------------
__global__ void pool_partial(const unsigned short* __restrict__ h2, const int* __restrict__ batch,
                             float* __restrict__ part, int n, int D, int S) {
  int g = blockIdx.x / S, sub = blockIdx.x - g * S;
  int lo, hi;
  { int a = 0, b = n; while (a < b) { int m = (a + b) >> 1; if (batch[m] < g) a = m + 1; else b = m; } lo = a; }
  { int a = lo, b = n; while (a < b) { int m = (a + b) >> 1; if (batch[m] < g + 1) a = m + 1; else b = m; } hi = a; }
  int t = threadIdx.x;  // 256 threads, 2 cols each
  float sx = 0.f, sy = 0.f;
  for (int r = lo + sub; r < hi; r += S) {
    unsigned v = *(const unsigned*)(h2 + (size_t)r * D + t * 2);
    sx += bf2f((unsigned short)(v & 0xffffu));
    sy += bf2f((unsigned short)(v >> 16));
  }
  float* o = part + (size_t)blockIdx.x * D + t * 2;
  o[0] = sx;
  o[1] = sy;
}

__global__ void pool_reduce(const float* __restrict__ part, const int* __restrict__ batch,
                            float* __restrict__ out, int n, int D, int S, int G) {
  int idx = blockIdx.x * blockDim.x + threadIdx.x;
  if (idx >= G * D) return;
  int g = idx / D, d = idx - g * D;
  int lo, hi;
  { int a = 0, b = n; while (a < b) { int m = (a + b) >> 1; if (batch[m] < g) a = m + 1; else b = m; } lo = a; }
  { int a = lo, b = n; while (a < b) { int m = (a + b) >> 1; if (batch[m] < g + 1) a = m + 1; else b = m; } hi = a; }
  float sum = 0.f;
  for (int k = 0; k < S; ++k) sum += part[(size_t)(g * S + k) * D + d];
  out[idx] = sum / (float)(hi - lo);
}

// ---------------- launcher ----------------
static inline size_t align256(size_t x) { return (x + 255) & ~(size_t)255; }

extern "C" void kernel_launch(void* const* d_in, const int* in_sizes, int n_in,
                              void* d_out, int out_size, void* d_ws, size_t ws_size,
                              hipStream_t stream) {
  const float* x = (const float*)d_in[0];
  // d_in[1] = edge_index (unused by the math)
  const int* batch = (const int*)d_in[2];
  const float* W0 = (const float*)d_in[3];
  const float* b0 = (const float*)d_in[4];
  const float* W1 = (const float*)d_in[5];
  const float* b1 = (const float*)d_in[6];
  const float* W2 = (const float*)d_in[7];
  const float* b2 = (const float*)d_in[8];
  float* out = (float*)d_out;

  const int Nn = in_sizes[2];                 // 100000 nodes
  const int DIN = 512, DH = 1024, DOUT = 512;
  const int G = out_size / DOUT;              // 128
  const int S = 8;                            // pool sub-blocks per graph
  const int Mpad = ((Nn + 255) / 256) * 256;  // 100096

  // workspace layout
  uint8_t* p = (uint8_t*)d_ws;
  unsigned short* W0p = (unsigned short*)p; p += align256((size_t)DH * DIN * 2);
  unsigned short* W1p = (unsigned short*)p; p += align256((size_t)DH * DH * 2);
  unsigned short* W2p = (unsigned short*)p; p += align256((size_t)DOUT * DH * 2);
  unsigned short* h2  = (unsigned short*)p; p += align256((size_t)Mpad * DOUT * 2);
  float* part         = (float*)p;          p += align256((size_t)G * S * DOUT * 4);
  size_t used = (size_t)(p - (uint8_t*)d_ws);
  size_t avail = ws_size > used ? ws_size - used : 0;
  size_t per_row = (size_t)(DIN + DH + DH) * 2;       // xb + h0 + h1 bytes per row
  long long chl = (long long)(avail / per_row);
  chl = (chl / 256) * 256;
  int CH = (int)(chl < 256 ? 256 : chl);
  if (CH > Mpad) CH = Mpad;
  unsigned short* xb = (unsigned short*)p; p += align256((size_t)CH * DIN * 2);
  unsigned short* h0 = (unsigned short*)p; p += align256((size_t)CH * DH * 2);
  unsigned short* h1 = (unsigned short*)p; p += align256((size_t)CH * DH * 2);

  // 1) weights: pack + convert to fragment-linear bf16
  pack_w<<<dim3((DH / 32) * (DIN / 32)), 256, 0, stream>>>(W0, W0p, DIN, DH);
  pack_w<<<dim3((DH / 32) * (DH / 32)), 256, 0, stream>>>(W1, W1p, DH, DH);
  pack_w<<<dim3((DOUT / 32) * (DH / 32)), 256, 0, stream>>>(W2, W2p, DH, DOUT);

  // 2) chunked 3-layer MLP (single chunk when ws allows)
  for (int off = 0; off < Mpad; off += CH) {
    int rows = Mpad - off; if (rows > CH) rows = CH;
    int nvalid = Nn - off;
    size_t cvt_threads = (size_t)rows * DIN / 8;
    int cvt_blocks = (int)((cvt_threads + 255) / 256);
    if (cvt_blocks > 2048) cvt_blocks = 2048;
    cvt_x<<<dim3(cvt_blocks), 256, 0, stream>>>(x + (size_t)off * DIN, xb, rows, nvalid, DIN);

    gemm_blds<<<dim3((rows / 256) * (DH / 128)), 256, 0, stream>>>(xb, W0p, b0, h0, DH, DIN);
    gemm_blds<<<dim3((rows / 256) * (DH / 128)), 256, 0, stream>>>(h0, W1p, b1, h1, DH, DH);
    gemm_blds<<<dim3((rows / 256) * (DOUT / 128)), 256, 0, stream>>>(
        h1, W2p, b2, h2 + (size_t)off * DOUT, DOUT, DH);
  }

  // 3) per-graph mean pool
  pool_partial<<<dim3(G * S), 256, 0, stream>>>(h2, batch, part, Nn, DOUT, S);
  pool_reduce<<<dim3((G * DOUT + 255) / 256), 256, 0, stream>>>(part, batch, out, Nn, DOUT, S, G);
}

// Round 7
// 732.072 us; speedup vs baseline: 1.0333x; 1.0333x over previous
//
#include <hip/hip_runtime.h>
#include <cstdint>
#include <cstddef>

// ---------------- types / helpers ----------------
typedef __bf16 bf16x8 __attribute__((ext_vector_type(8)));
typedef float f32x4 __attribute__((ext_vector_type(4)));

__device__ __forceinline__ unsigned short f2bf(float f) {
  unsigned u = __float_as_uint(f);
  u += 0x7fffu + ((u >> 16) & 1u);   // RNE
  return (unsigned short)(u >> 16);
}
__device__ __forceinline__ float bf2f(unsigned short s) {
  return __uint_as_float(((unsigned)s) << 16);
}

// async global->LDS, 16B per lane, linear dest (wave-uniform base + lane*16)
__device__ __forceinline__ void gld_lds16(const void* g, void* l) {
  __builtin_amdgcn_global_load_lds(
      (const __attribute__((address_space(1))) void*)g,
      (__attribute__((address_space(3))) void*)l, 16, 0, 0);
}

#define BARM() do { __builtin_amdgcn_s_barrier(); asm volatile("" ::: "memory"); } while (0)
#define VMCNT(n) asm volatile("s_waitcnt vmcnt(" #n ")" ::: "memory")
#define LGKM0()  do { asm volatile("s_waitcnt lgkmcnt(0)" ::: "memory"); \
                      __builtin_amdgcn_sched_barrier(0); } while (0)

// ---------------- pack W [K][N] f32 -> Wp fragment-linear bf16 ----------------
// Wp element for (n,k): nt=n/16, kq=k/32, lane=(n%16)+((k%32)/8)*16, e=k%8
// -> Wp[((nt*KQ + kq)*64 + lane)*8 + e]. A wave's B-frag (16 rows x k32-slice)
// is then ONE coalesced 1KB chunk: base + lane*16B.
__global__ void pack_w(const float* __restrict__ w, unsigned short* __restrict__ wp,
                       int K, int N) {
  __shared__ float tile[32][33];
  int nt32 = N >> 5;
  int bx = blockIdx.x % nt32;   // n 32-tile
  int by = blockIdx.x / nt32;   // k 32-tile == kq
  int tx = threadIdx.x & 31, ty = threadIdx.x >> 5;  // 32x8
#pragma unroll
  for (int r = 0; r < 32; r += 8)
    tile[ty + r][tx] = w[(size_t)(by * 32 + ty + r) * N + bx * 32 + tx];  // [k-loc][n-loc]
  __syncthreads();
  int KQ = K >> 5;
  int flat = threadIdx.x * 4;          // 1024 bf16 out per 32x32 tile
  int c = flat >> 9;                   // n-half -> nt = bx*2 + c
  int l = (flat >> 3) & 63;
  int e0 = flat & 7;                   // 0 or 4
  int nl = c * 16 + (l & 15);
  int kl = (l >> 4) * 8 + e0;
  unsigned short* o = wp + ((size_t)((bx * 2 + c) * KQ + by) * 64 + l) * 8 + e0;
#pragma unroll
  for (int e = 0; e < 4; ++e) o[e] = f2bf(tile[kl + e][nl]);
}

// ---------------- x f32 -> bf16 (chunk, zero-pad rows >= nvalid) ----------------
__global__ void cvt_x(const float* __restrict__ x, unsigned short* __restrict__ xb,
                      int rows, int nvalid, int D) {
  size_t total = (size_t)rows * D / 8;
  for (size_t i = (size_t)blockIdx.x * blockDim.x + threadIdx.x; i < total;
       i += (size_t)gridDim.x * blockDim.x) {
    size_t e = i * 8;
    int row = (int)(e / (size_t)D);
    uint4 ov;
    if (row < nvalid) {
      const float4* s = (const float4*)(x + e);
      float4 v0 = s[0], v1 = s[1];
      ov.x = (unsigned)f2bf(v0.x) | ((unsigned)f2bf(v0.y) << 16);
      ov.y = (unsigned)f2bf(v0.z) | ((unsigned)f2bf(v0.w) << 16);
      ov.z = (unsigned)f2bf(v1.x) | ((unsigned)f2bf(v1.y) << 16);
      ov.w = (unsigned)f2bf(v1.z) | ((unsigned)f2bf(v1.w) << 16);
    } else {
      ov.x = ov.y = ov.z = ov.w = 0u;
    }
    *(uint4*)(xb + e) = ov;
  }
}

// ---------------- 256x128 GEMM, BK=64, A-only LDS, counted vmcnt ----------------
// 256 threads = 4 waves (2M x 2N); per-wave output 128x64; 2 blocks/CU.
// Round-6 lesson: MfmaUtil == MFMA-work/wall at ~30% across 3 schedules; the
// wall is per-tile fixed cost (2 barriers + vmcnt(0) drain every BK=32).
// Fixes: BK=64 (half the barriers per FLOP), ONE barrier per tile, and
// counted vmcnt that never drains to 0 mid-loop (T4):
//   tile t (slot s=t&1), per wave VM issue order [carried bc(4)] then:
//   kq0: ds_read A-kq0(8); stage A(t+1)->s^1 (8 gld_lds); load bn=B(2t+1) (4);
//        vmcnt(12) certifies bc (leaves stage+bn in flight); lgkm0; 32 MFMA(bc)
//   kq1: ds_read A-kq1(8); load bc=B(2t+2) (4);
//        vmcnt(4) certifies stage+bn (~1300cyc old; leaves bc in flight);
//        lgkm0; 32 MFMA(bn); BAR
// Race audit: stage targets s^1 (no reader this tile); every wave's reads of
// slot s complete before its lgkm0 -> before BAR; stage certified by each
// wave's vmcnt(4) before BAR -> tile t+1 may read s^1 after BAR.
// Swizzle (BK=64): granule g=elem/8 stored at g^(row&7); inverse applied on
// the global source (linear LDS dest), forward on ds_read (rule #21).
__device__ __forceinline__ bf16x8 read_frag64(const unsigned short* region, int row, int kel) {
  int ke = kel ^ ((row & 7) << 3);
  return *(const bf16x8*)(region + row * 64 + ke);
}

__device__ __forceinline__ void stage_a64(const unsigned short* gpanel, int K, int kofs,
                                          unsigned short* region, int tid) {
#pragma unroll
  for (int p = 0; p < 8; ++p) {
    int row = p * 32 + (tid >> 3);
    int ke = ((tid & 7) * 8) ^ ((row & 7) << 3);  // inverse-swizzled source
    gld_lds16(gpanel + (size_t)row * K + kofs + ke, region + p * 2048 + tid * 8);
  }
}

__device__ __forceinline__ void load_b4(const unsigned short* wpb, int KQ, int kq, int l,
                                        bf16x8* b) {
#pragma unroll
  for (int nn = 0; nn < 4; ++nn)
    b[nn] = *(const bf16x8*)(wpb + ((size_t)(nn * KQ + kq) * 64 + l) * 8);
}

#define MFMA32(BV)                                                              \
  do {                                                                          \
    __builtin_amdgcn_s_setprio(1);                                              \
    _Pragma("unroll") for (int mm = 0; mm < 8; ++mm)                            \
        _Pragma("unroll") for (int nn = 0; nn < 4; ++nn)                        \
            acc[mm][nn] = __builtin_amdgcn_mfma_f32_16x16x32_bf16(              \
                a[mm], BV[nn], acc[mm][nn], 0, 0, 0);                           \
    __builtin_amdgcn_s_setprio(0);                                              \
  } while (0)

__global__ __launch_bounds__(256, 2) void gemm_bk64(
    const unsigned short* __restrict__ A,   // [M][K] bf16
    const unsigned short* __restrict__ Wp,  // packed [N/16][K/32][64][8] bf16
    const float* __restrict__ bias,         // [N] f32
    unsigned short* __restrict__ C,         // [M][N] bf16
    int N, int K) {
  __shared__ alignas(16) unsigned short lds[2][16384];   // 2 x A[256][64] = 64 KiB
  const int tid = threadIdx.x;
  const int w = tid >> 6, l = tid & 63;
  const int wm = w >> 1, wn = w & 1;
  const int lc = l & 15, lk8 = (l >> 4) * 8;

  // T1: bijective XCD swizzle (m204); bn-fast so an XCD chunk reuses A panels.
  const int nbn = N >> 7;
  const int nwg = gridDim.x;
  const int q = nwg >> 3, rr = nwg & 7;
  const int xcd = blockIdx.x & 7, ib = blockIdx.x >> 3;
  const int bswz = (xcd < rr ? xcd * (q + 1) : rr * (q + 1) + (xcd - rr) * q) + ib;
  const int bm = bswz / nbn, bn = bswz - bm * nbn;

  const unsigned short* Ap = A + (size_t)bm * 256 * K;
  const int KQ = K >> 5;
  const unsigned short* wpb = Wp + ((size_t)(bn * 8 + wn * 4) * KQ * 64) * 8;
  const int T = K >> 6;

  f32x4 acc[8][4] = {};
  bf16x8 a[8], bc[4], bn_[4];

  // prologue: A tile0 -> slot0; B frags for kq=0 -> bc
  stage_a64(Ap, K, 0, &lds[0][0], tid);
  load_b4(wpb, KQ, 0, l, bc);
  VMCNT(0);
  BARM();

  for (int t = 0; t < T; ++t) {
    const int s = t & 1;
    const unsigned short* As = &lds[s][0];
    unsigned short* Sn = &lds[s ^ 1][0];

    // ---- kq0 sub-phase ----
#pragma unroll
    for (int mm = 0; mm < 8; ++mm) a[mm] = read_frag64(As, wm * 128 + mm * 16 + lc, lk8);
    if (t + 1 < T) stage_a64(Ap, K, (t + 1) * 64, Sn, tid);
    load_b4(wpb, KQ, 2 * t + 1, l, bn_);
    if (t + 1 < T) { VMCNT(12); } else { VMCNT(4); }   // certify carried bc
    LGKM0();
    MFMA32(bc);

    // ---- kq1 sub-phase ----
#pragma unroll
    for (int mm = 0; mm < 8; ++mm) a[mm] = read_frag64(As, wm * 128 + mm * 16 + lc, 32 + lk8);
    if (t + 1 < T) load_b4(wpb, KQ, 2 * t + 2, l, bc);
    if (t + 1 < T) { VMCNT(4); } else { VMCNT(0); }    // certify stage+bn_, keep bc in flight
    LGKM0();
    MFMA32(bn_);
    BARM();   // single barrier per tile: slot handoff certified
  }

  // ---- epilogue: acc -> LDS (granule-XOR) -> coalesced dwordx4 stores ----
  // eps = [128][128] bf16 = 32 KiB (fits in slot 0).
  unsigned short* eps = &lds[0][0];
  float bv[4];
#pragma unroll
  for (int nn = 0; nn < 4; ++nn) bv[nn] = bias[bn * 128 + wn * 64 + nn * 16 + lc];

#pragma unroll
  for (int r = 0; r < 2; ++r) {
    if (wm == r) {
#pragma unroll
      for (int mm = 0; mm < 8; ++mm) {
#pragma unroll
        for (int nn = 0; nn < 4; ++nn) {
          int lcol = wn * 64 + nn * 16 + lc;
#pragma unroll
          for (int j = 0; j < 4; ++j) {
            int lrow = mm * 16 + (l >> 4) * 4 + j;
            int g = lcol >> 3, e = lcol & 7;
            float v = fmaxf(acc[mm][nn][j] + bv[nn], 0.0f);
            eps[lrow * 128 + ((g ^ (lrow & 15)) << 3) + e] = f2bf(v);
          }
        }
      }
    }
    BARM();
#pragma unroll
    for (int it = 0; it < 8; ++it) {
      int flat = it * 256 + tid;          // 2048 = 128 rows x 16 col-granules
      int lrow = flat >> 4, cb = flat & 15;
      uint4 v = *(const uint4*)&eps[lrow * 128 + (((cb ^ (lrow & 15))) << 3)];
      *(uint4*)&C[(size_t)(bm * 256 + r * 128 + lrow) * N + bn * 128 + cb * 8] = v;
    }
    BARM();
  }
}

// ---------------- segment mean pool (split: S sub-blocks per graph + reduce) ----------------
__global__ void pool_partial(const unsigned short* __restrict__ h2, const int* __restrict__ batch,
                             float* __restrict__ part, int n, int D, int S) {
  int g = blockIdx.x / S, sub = blockIdx.x - g * S;
  int lo, hi;
  { int a = 0, b = n; while (a < b) { int m = (a + b) >> 1; if (batch[m] < g) a = m + 1; else b = m; } lo = a; }
  { int a = lo, b = n; while (a < b) { int m = (a + b) >> 1; if (batch[m] < g + 1) a = m + 1; else b = m; } hi = a; }
  int t = threadIdx.x;  // 256 threads, 2 cols each
  float sx = 0.f, sy = 0.f;
  for (int r = lo + sub; r < hi; r += S) {
    unsigned v = *(const unsigned*)(h2 + (size_t)r * D + t * 2);
    sx += bf2f((unsigned short)(v & 0xffffu));
    sy += bf2f((unsigned short)(v >> 16));
  }
  float* o = part + (size_t)blockIdx.x * D + t * 2;
  o[0] = sx;
  o[1] = sy;
}

__global__ void pool_reduce(const float* __restrict__ part, const int* __restrict__ batch,
                            float* __restrict__ out, int n, int D, int S, int G) {
  int idx = blockIdx.x * blockDim.x + threadIdx.x;
  if (idx >= G * D) return;
  int g = idx / D, d = idx - g * D;
  int lo, hi;
  { int a = 0, b = n; while (a < b) { int m = (a + b) >> 1; if (batch[m] < g) a = m + 1; else b = m; } lo = a; }
  { int a = lo, b = n; while (a < b) { int m = (a + b) >> 1; if (batch[m] < g + 1) a = m + 1; else b = m; } hi = a; }
  float sum = 0.f;
  for (int k = 0; k < S; ++k) sum += part[(size_t)(g * S + k) * D + d];
  out[idx] = sum / (float)(hi - lo);
}

// ---------------- launcher ----------------
static inline size_t align256(size_t x) { return (x + 255) & ~(size_t)255; }

extern "C" void kernel_launch(void* const* d_in, const int* in_sizes, int n_in,
                              void* d_out, int out_size, void* d_ws, size_t ws_size,
                              hipStream_t stream) {
  const float* x = (const float*)d_in[0];
  // d_in[1] = edge_index (unused by the math)
  const int* batch = (const int*)d_in[2];
  const float* W0 = (const float*)d_in[3];
  const float* b0 = (const float*)d_in[4];
  const float* W1 = (const float*)d_in[5];
  const float* b1 = (const float*)d_in[6];
  const float* W2 = (const float*)d_in[7];
  const float* b2 = (const float*)d_in[8];
  float* out = (float*)d_out;

  const int Nn = in_sizes[2];                 // 100000 nodes
  const int DIN = 512, DH = 1024, DOUT = 512;
  const int G = out_size / DOUT;              // 128
  const int S = 8;                            // pool sub-blocks per graph
  const int Mpad = ((Nn + 255) / 256) * 256;  // 100096

  // workspace layout
  uint8_t* p = (uint8_t*)d_ws;
  unsigned short* W0p = (unsigned short*)p; p += align256((size_t)DH * DIN * 2);
  unsigned short* W1p = (unsigned short*)p; p += align256((size_t)DH * DH * 2);
  unsigned short* W2p = (unsigned short*)p; p += align256((size_t)DOUT * DH * 2);
  unsigned short* h2  = (unsigned short*)p; p += align256((size_t)Mpad * DOUT * 2);
  float* part         = (float*)p;          p += align256((size_t)G * S * DOUT * 4);
  size_t used = (size_t)(p - (uint8_t*)d_ws);
  size_t avail = ws_size > used ? ws_size - used : 0;
  size_t per_row = (size_t)(DIN + DH + DH) * 2;       // xb + h0 + h1 bytes per row
  long long chl = (long long)(avail / per_row);
  chl = (chl / 256) * 256;
  int CH = (int)(chl < 256 ? 256 : chl);
  if (CH > Mpad) CH = Mpad;
  unsigned short* xb = (unsigned short*)p; p += align256((size_t)CH * DIN * 2);
  unsigned short* h0 = (unsigned short*)p; p += align256((size_t)CH * DH * 2);
  unsigned short* h1 = (unsigned short*)p; p += align256((size_t)CH * DH * 2);

  // 1) weights: pack + convert to fragment-linear bf16
  pack_w<<<dim3((DH / 32) * (DIN / 32)), 256, 0, stream>>>(W0, W0p, DIN, DH);
  pack_w<<<dim3((DH / 32) * (DH / 32)), 256, 0, stream>>>(W1, W1p, DH, DH);
  pack_w<<<dim3((DOUT / 32) * (DH / 32)), 256, 0, stream>>>(W2, W2p, DH, DOUT);

  // 2) chunked 3-layer MLP (single chunk when ws allows)
  for (int off = 0; off < Mpad; off += CH) {
    int rows = Mpad - off; if (rows > CH) rows = CH;
    int nvalid = Nn - off;
    size_t cvt_threads = (size_t)rows * DIN / 8;
    int cvt_blocks = (int)((cvt_threads + 255) / 256);
    if (cvt_blocks > 2048) cvt_blocks = 2048;
    cvt_x<<<dim3(cvt_blocks), 256, 0, stream>>>(x + (size_t)off * DIN, xb, rows, nvalid, DIN);

    gemm_bk64<<<dim3((rows / 256) * (DH / 128)), 256, 0, stream>>>(xb, W0p, b0, h0, DH, DIN);
    gemm_bk64<<<dim3((rows / 256) * (DH / 128)), 256, 0, stream>>>(h0, W1p, b1, h1, DH, DH);
    gemm_bk64<<<dim3((rows / 256) * (DOUT / 128)), 256, 0, stream>>>(
        h1, W2p, b2, h2 + (size_t)off * DOUT, DOUT, DH);
  }

  // 3) per-graph mean pool
  pool_partial<<<dim3(G * S), 256, 0, stream>>>(h2, batch, part, Nn, DOUT, S);
  pool_reduce<<<dim3((G * DOUT + 255) / 256), 256, 0, stream>>>(part, batch, out, Nn, DOUT, S, G);
}

// Round 8
// 674.917 us; speedup vs baseline: 1.1208x; 1.0847x over previous
//
#include <hip/hip_runtime.h>
#include <cstdint>
#include <cstddef>

// ---------------- types / helpers ----------------
typedef __bf16 bf16x8 __attribute__((ext_vector_type(8)));
typedef float f32x4 __attribute__((ext_vector_type(4)));

__device__ __forceinline__ unsigned short f2bf(float f) {
  unsigned u = __float_as_uint(f);
  u += 0x7fffu + ((u >> 16) & 1u);   // RNE
  return (unsigned short)(u >> 16);
}
__device__ __forceinline__ float bf2f(unsigned short s) {
  return __uint_as_float(((unsigned)s) << 16);
}

// async global->LDS, 16B per lane, linear dest (wave-uniform base + lane*16)
__device__ __forceinline__ void gld_lds16(const void* g, void* l) {
  __builtin_amdgcn_global_load_lds(
      (const __attribute__((address_space(1))) void*)g,
      (__attribute__((address_space(3))) void*)l, 16, 0, 0);
}

#define BARM() do { __builtin_amdgcn_s_barrier(); asm volatile("" ::: "memory"); } while (0)
#define VMCNT(n) asm volatile("s_waitcnt vmcnt(" #n ")" ::: "memory")
#define LGKM0()  do { asm volatile("s_waitcnt lgkmcnt(0)" ::: "memory"); \
                      __builtin_amdgcn_sched_barrier(0); } while (0)

// ---------------- transpose + convert W [K][N] f32 -> Wt [N][K] bf16 ----------------
__global__ void transpose_w(const float* __restrict__ w, unsigned short* __restrict__ wt,
                            int K, int N) {
  __shared__ float tile[32][33];
  int nt = N >> 5;
  int bx = blockIdx.x % nt;   // n tile
  int by = blockIdx.x / nt;   // k tile
  int tx = threadIdx.x & 31, ty = threadIdx.x >> 5;  // 32x8
#pragma unroll
  for (int r = 0; r < 32; r += 8)
    tile[ty + r][tx] = w[(size_t)(by * 32 + ty + r) * N + bx * 32 + tx];
  __syncthreads();
#pragma unroll
  for (int r = 0; r < 32; r += 8)
    wt[(size_t)(bx * 32 + ty + r) * K + by * 32 + tx] = f2bf(tile[tx][ty + r]);
}

// ---------------- x f32 -> bf16 (chunk, zero-pad rows >= nvalid) ----------------
__global__ void cvt_x(const float* __restrict__ x, unsigned short* __restrict__ xb,
                      int rows, int nvalid, int D) {
  size_t total = (size_t)rows * D / 8;
  for (size_t i = (size_t)blockIdx.x * blockDim.x + threadIdx.x; i < total;
       i += (size_t)gridDim.x * blockDim.x) {
    size_t e = i * 8;
    int row = (int)(e / (size_t)D);
    uint4 ov;
    if (row < nvalid) {
      const float4* s = (const float4*)(x + e);
      float4 v0 = s[0], v1 = s[1];
      ov.x = (unsigned)f2bf(v0.x) | ((unsigned)f2bf(v0.y) << 16);
      ov.y = (unsigned)f2bf(v0.z) | ((unsigned)f2bf(v0.w) << 16);
      ov.z = (unsigned)f2bf(v1.x) | ((unsigned)f2bf(v1.y) << 16);
      ov.w = (unsigned)f2bf(v1.z) | ((unsigned)f2bf(v1.w) << 16);
    } else {
      ov.x = ov.y = ov.z = ov.w = 0u;
    }
    *(uint4*)(xb + e) = ov;
  }
}

// ---------------- 256x256 8-phase GEMM core (round-4 proven) ----------------
__device__ __forceinline__ bf16x8 read_frag(const unsigned short* region, int row, int kel) {
  int ke = kel ^ (((row >> 1) & 3) << 3);
  return *(const bf16x8*)(region + row * 32 + ke);
}

__device__ __forceinline__ void stage_half(const unsigned short* gpanel, int K, int kofs,
                                           unsigned short* region, int tid) {
#pragma unroll
  for (int r = 0; r < 2; ++r) {
    int row = r * 128 + (tid >> 2);
    int ke = ((tid & 3) * 8) ^ (((row >> 1) & 3) << 3);  // inverse-swizzled source
    gld_lds16(gpanel + (size_t)row * K + kofs + ke, region + r * 4096 + tid * 8);
  }
}

#define MFMA16(MB, BV)                                                          \
  do {                                                                          \
    __builtin_amdgcn_s_setprio(1);                                              \
    _Pragma("unroll") for (int mm = 0; mm < 4; ++mm) {                          \
      _Pragma("unroll") for (int nn = 0; nn < 4; ++nn)                          \
        acc[(MB) + mm][nn] = __builtin_amdgcn_mfma_f32_16x16x32_bf16(           \
            av[mm], BV[nn], acc[(MB) + mm][nn], 0, 0, 0);                       \
    }                                                                           \
    __builtin_amdgcn_s_setprio(0);                                              \
  } while (0)

// Shared K-loop body for both gemm variants. Defines acc[8][4] and runs the
// 8-phase schedule; caller provides epilogue.
#define GEMM_PREAMBLE_AND_KLOOP()                                               \
  const int tid = threadIdx.x;                                                  \
  const int w = tid >> 6, l = tid & 63;                                         \
  const int wm = w >> 2, wn = w & 3;                                            \
  const int lc = l & 15, lk8 = (l >> 4) * 8;                                    \
  const int nbn = N >> 8;                                                       \
  const int nwg = gridDim.x;                                                    \
  const int q = nwg >> 3, rr = nwg & 7;                                         \
  const int xcd = blockIdx.x & 7, ib = blockIdx.x >> 3;                         \
  const int bswz = (xcd < rr ? xcd * (q + 1) : rr * (q + 1) + (xcd - rr) * q) + ib; \
  const int bm = bswz / nbn, bn = bswz - bm * nbn;                              \
  const unsigned short* Ap = A + (size_t)bm * 256 * K;                          \
  const unsigned short* Bp = Bt + (size_t)bn * 256 * K;                         \
  const int T = K >> 6;                                                         \
  f32x4 acc[8][4] = {};                                                         \
  stage_half(Ap, K, 0, &lds[0][0][0][0][0], tid);                               \
  stage_half(Bp, K, 0, &lds[0][1][0][0][0], tid);                               \
  stage_half(Ap, K, 32, &lds[0][0][1][0][0], tid);                              \
  stage_half(Bp, K, 32, &lds[0][1][1][0][0], tid);                              \
  stage_half(Ap, K, 64, &lds[1][0][0][0][0], tid);                              \
  stage_half(Bp, K, 64, &lds[1][1][0][0][0], tid);                              \
  VMCNT(4);                                                                     \
  BARM();                                                                       \
  for (int t = 0; t < T; ++t) {                                                 \
    const int s = t & 1;                                                        \
    const unsigned short* Ak0 = &lds[s][0][0][0][0];                            \
    const unsigned short* Ak1 = &lds[s][0][1][0][0];                            \
    const unsigned short* Bk0 = &lds[s][1][0][0][0];                            \
    const unsigned short* Bk1 = &lds[s][1][1][0][0];                            \
    unsigned short* nAk1 = &lds[s ^ 1][0][1][0][0];                             \
    unsigned short* nBk1 = &lds[s ^ 1][1][1][0][0];                             \
    unsigned short* cAk0 = &lds[s][0][0][0][0];                                 \
    unsigned short* cBk0 = &lds[s][1][0][0][0];                                 \
    bf16x8 av[4], b0[4], b1[4];                                                 \
    _Pragma("unroll") for (int mm = 0; mm < 4; ++mm)                            \
        av[mm] = read_frag(Ak0, wm * 128 + mm * 16 + lc, lk8);                  \
    _Pragma("unroll") for (int nn = 0; nn < 4; ++nn)                            \
        b0[nn] = read_frag(Bk0, wn * 64 + nn * 16 + lc, lk8);                   \
    if (t + 1 < T) stage_half(Ap, K, (t + 1) * 64 + 32, nAk1, tid);             \
    BARM(); LGKM0(); MFMA16(0, b0); BARM();                                     \
    _Pragma("unroll") for (int mm = 0; mm < 4; ++mm)                            \
        av[mm] = read_frag(Ak0, wm * 128 + (4 + mm) * 16 + lc, lk8);            \
    if (t + 1 < T) stage_half(Bp, K, (t + 1) * 64 + 32, nBk1, tid);             \
    BARM(); LGKM0(); MFMA16(4, b0); BARM();                                     \
    _Pragma("unroll") for (int mm = 0; mm < 4; ++mm)                            \
        av[mm] = read_frag(Ak1, wm * 128 + mm * 16 + lc, lk8);                  \
    _Pragma("unroll") for (int nn = 0; nn < 4; ++nn)                            \
        b1[nn] = read_frag(Bk1, wn * 64 + nn * 16 + lc, lk8);                   \
    if (t + 2 < T) stage_half(Ap, K, (t + 2) * 64, cAk0, tid);                  \
    BARM(); LGKM0(); MFMA16(0, b1); BARM();                                     \
    _Pragma("unroll") for (int mm = 0; mm < 4; ++mm)                            \
        av[mm] = read_frag(Ak1, wm * 128 + (4 + mm) * 16 + lc, lk8);            \
    if (t + 2 < T) { stage_half(Bp, K, (t + 2) * 64, cBk0, tid); VMCNT(4); }    \
    else { VMCNT(0); }                                                          \
    BARM(); LGKM0(); MFMA16(4, b1); BARM();                                     \
  }

__global__ __launch_bounds__(512, 2) void gemm256(
    const unsigned short* __restrict__ A,   // [M][K] bf16
    const unsigned short* __restrict__ Bt,  // [N][K] bf16
    const float* __restrict__ bias,         // [N] f32
    unsigned short* __restrict__ C,         // [M][N] bf16
    int N, int K) {
  __shared__ alignas(16) unsigned short lds[2][2][2][256][32];   // 128 KiB
  GEMM_PREAMBLE_AND_KLOOP();

  // ---- epilogue: acc -> LDS (row-XOR swizzle) -> coalesced dwordx4 stores ----
  unsigned short* eps = &lds[0][0][0][0][0];
  float bv[4];
#pragma unroll
  for (int nn = 0; nn < 4; ++nn) bv[nn] = bias[bn * 256 + wn * 64 + nn * 16 + lc];

#pragma unroll
  for (int r = 0; r < 2; ++r) {
    if (wm == r) {
#pragma unroll
      for (int mm = 0; mm < 8; ++mm) {
#pragma unroll
        for (int nn = 0; nn < 4; ++nn) {
          int lcol = wn * 64 + nn * 16 + lc;
#pragma unroll
          for (int j = 0; j < 4; ++j) {
            int lrow = mm * 16 + (l >> 4) * 4 + j;
            float v = fmaxf(acc[mm][nn][j] + bv[nn], 0.0f);
            eps[lrow * 256 + (lcol ^ (((lrow >> 2) & 3) << 4))] = f2bf(v);
          }
        }
      }
    }
    BARM();
#pragma unroll
    for (int it = 0; it < 8; ++it) {
      int flat = it * 512 + tid;          // 4096 = 128 rows x 32 col-granules
      int lrow = flat >> 5, cb = flat & 31;
      int ce = (cb * 8) ^ (((lrow >> 2) & 3) << 4);
      uint4 v = *(const uint4*)&eps[lrow * 256 + ce];
      *(uint4*)&C[(size_t)(bm * 256 + r * 128 + lrow) * N + bn * 256 + cb * 8] = v;
    }
    BARM();
  }
}

// Last layer: identical K-loop, but instead of writing C, segment-sum the
// relu'd outputs per graph (batch sorted; pad rows -> sentinel -1) and
// atomicAdd into part[G][N]. Skips the h2 round-trip and pool_partial.
__global__ __launch_bounds__(512, 2) void gemm_pool(
    const unsigned short* __restrict__ A,   // [M][K] bf16 (chunk base)
    const unsigned short* __restrict__ Bt,  // [N][K] bf16
    const float* __restrict__ bias,         // [N] f32
    const int* __restrict__ batch,          // [Nn] sorted graph ids (global)
    float* __restrict__ part,               // [G][N] f32 accumulators
    int N, int K, int row0, int Nn) {       // row0 = chunk offset in global rows
  __shared__ alignas(16) unsigned short lds[2][2][2][256][32];   // 128 KiB
  GEMM_PREAMBLE_AND_KLOOP();

  unsigned short* eps = &lds[0][0][0][0][0];
  int* batchLS = (int*)&lds[1][0][0][0][0];   // slot 1 is free post-loop
  // stage batch ids for this block's 256 rows (global rows row0+bm*256+i)
  if (tid < 256) {
    int grow = row0 + bm * 256 + tid;
    batchLS[tid] = (grow < Nn) ? batch[grow] : -1;
  }
  float bv[4];
#pragma unroll
  for (int nn = 0; nn < 4; ++nn) bv[nn] = bias[bn * 256 + wn * 64 + nn * 16 + lc];

#pragma unroll
  for (int r = 0; r < 2; ++r) {
    if (wm == r) {
#pragma unroll
      for (int mm = 0; mm < 8; ++mm) {
#pragma unroll
        for (int nn = 0; nn < 4; ++nn) {
          int lcol = wn * 64 + nn * 16 + lc;
#pragma unroll
          for (int j = 0; j < 4; ++j) {
            int lrow = mm * 16 + (l >> 4) * 4 + j;
            float v = fmaxf(acc[mm][nn][j] + bv[nn], 0.0f);
            eps[lrow * 256 + (lcol ^ (((lrow >> 2) & 3) << 4))] = f2bf(v);
          }
        }
      }
    }
    BARM();
    // column scan: thread -> (col = tid&255, rows half*64..half*64+63)
    {
      int col = tid & 255;
      int half = tid >> 8;
      int gcur = -2;
      float run = 0.f;
      int gcolbase = bn * 256 + col;
      for (int i = 0; i < 64; ++i) {
        int lr = half * 64 + i;
        int g = batchLS[r * 128 + lr];
        if (g != gcur) {
          if (gcur >= 0) atomicAdd(&part[(size_t)gcur * N + gcolbase], run);
          gcur = g; run = 0.f;
        }
        run += bf2f(eps[lr * 256 + (col ^ (((lr >> 2) & 3) << 4))]);
      }
      if (gcur >= 0) atomicAdd(&part[(size_t)gcur * N + gcolbase], run);
    }
    BARM();
  }
}

// ---------------- pool finalize ----------------
__global__ void zero_part(float* __restrict__ part, int n) {
  int i = blockIdx.x * blockDim.x + threadIdx.x;
  if (i < n) part[i] = 0.f;
}

__global__ void pool_div(const float* __restrict__ part, const int* __restrict__ batch,
                         float* __restrict__ out, int n, int D, int G) {
  int idx = blockIdx.x * blockDim.x + threadIdx.x;
  if (idx >= G * D) return;
  int g = idx / D;
  int lo, hi;
  { int a = 0, b = n; while (a < b) { int m = (a + b) >> 1; if (batch[m] < g) a = m + 1; else b = m; } lo = a; }
  { int a = lo, b = n; while (a < b) { int m = (a + b) >> 1; if (batch[m] < g + 1) a = m + 1; else b = m; } hi = a; }
  out[idx] = part[idx] / (float)(hi - lo);
}

// ---------------- launcher ----------------
static inline size_t align256(size_t x) { return (x + 255) & ~(size_t)255; }

extern "C" void kernel_launch(void* const* d_in, const int* in_sizes, int n_in,
                              void* d_out, int out_size, void* d_ws, size_t ws_size,
                              hipStream_t stream) {
  const float* x = (const float*)d_in[0];
  // d_in[1] = edge_index (unused by the math)
  const int* batch = (const int*)d_in[2];
  const float* W0 = (const float*)d_in[3];
  const float* b0 = (const float*)d_in[4];
  const float* W1 = (const float*)d_in[5];
  const float* b1 = (const float*)d_in[6];
  const float* W2 = (const float*)d_in[7];
  const float* b2 = (const float*)d_in[8];
  float* out = (float*)d_out;

  const int Nn = in_sizes[2];                 // 100000 nodes
  const int DIN = 512, DH = 1024, DOUT = 512;
  const int G = out_size / DOUT;              // 128
  const int Mpad = ((Nn + 255) / 256) * 256;  // 100096

  // workspace layout (h2 eliminated)
  uint8_t* p = (uint8_t*)d_ws;
  unsigned short* W0t = (unsigned short*)p; p += align256((size_t)DH * DIN * 2);
  unsigned short* W1t = (unsigned short*)p; p += align256((size_t)DH * DH * 2);
  unsigned short* W2t = (unsigned short*)p; p += align256((size_t)DOUT * DH * 2);
  float* part         = (float*)p;          p += align256((size_t)G * DOUT * 4);
  size_t used = (size_t)(p - (uint8_t*)d_ws);
  size_t avail = ws_size > used ? ws_size - used : 0;
  size_t per_row = (size_t)(DIN + DH + DH) * 2;       // xb + h0 + h1 bytes per row
  long long chl = (long long)(avail / per_row);
  chl = (chl / 256) * 256;
  int CH = (int)(chl < 256 ? 256 : chl);
  if (CH > Mpad) CH = Mpad;
  unsigned short* xb = (unsigned short*)p; p += align256((size_t)CH * DIN * 2);
  unsigned short* h0 = (unsigned short*)p; p += align256((size_t)CH * DH * 2);
  unsigned short* h1 = (unsigned short*)p; p += align256((size_t)CH * DH * 2);

  // 0) zero the pooling accumulators
  zero_part<<<dim3((G * DOUT + 255) / 256), 256, 0, stream>>>(part, G * DOUT);

  // 1) weights: transpose + convert to bf16 [N][K]
  transpose_w<<<dim3((DIN / 32) * (DH / 32)), 256, 0, stream>>>(W0, W0t, DIN, DH);
  transpose_w<<<dim3((DH / 32) * (DH / 32)), 256, 0, stream>>>(W1, W1t, DH, DH);
  transpose_w<<<dim3((DH / 32) * (DOUT / 32)), 256, 0, stream>>>(W2, W2t, DH, DOUT);

  // 2) chunked 3-layer MLP (single chunk when ws allows); L2 fuses the pool
  for (int off = 0; off < Mpad; off += CH) {
    int rows = Mpad - off; if (rows > CH) rows = CH;
    int nvalid = Nn - off;
    size_t cvt_threads = (size_t)rows * DIN / 8;
    int cvt_blocks = (int)((cvt_threads + 255) / 256);
    if (cvt_blocks > 2048) cvt_blocks = 2048;
    cvt_x<<<dim3(cvt_blocks), 256, 0, stream>>>(x + (size_t)off * DIN, xb, rows, nvalid, DIN);

    gemm256<<<dim3((rows / 256) * (DH / 256)), 512, 0, stream>>>(xb, W0t, b0, h0, DH, DIN);
    gemm256<<<dim3((rows / 256) * (DH / 256)), 512, 0, stream>>>(h0, W1t, b1, h1, DH, DH);
    gemm_pool<<<dim3((rows / 256) * (DOUT / 256)), 512, 0, stream>>>(
        h1, W2t, b2, batch, part, DOUT, DH, off, Nn);
  }

  // 3) finalize: mean = sum / count
  pool_div<<<dim3((G * DOUT + 255) / 256), 256, 0, stream>>>(part, batch, out, Nn, DOUT, G);
}